// Round 8
// baseline (44.792 us; speedup 1.0000x reference)
//
#include <hip/hip_runtime.h>
#include <hip/hip_bf16.h>

typedef __attribute__((ext_vector_type(8))) short short8;
typedef __attribute__((ext_vector_type(4))) float floatx4;
typedef __attribute__((ext_vector_type(2))) float floatx2;

#define B_ROWS 8192
#define DIM    128
#define NSPLIT 16
#define JSPAN  (B_ROWS / NSPLIT)        // 512 cols per split
#define NTILE  (JSPAN / 16)             // 32 j-tiles of 16 cols
#define WAVES  4
#define RPW    64                       // rows per wave (4 x 16-row MFMA sets)
#define BM     (WAVES * RPW)            // 256 rows per block
#define NRB    (B_ROWS / BM)            // 32 row-blocks -> 512 blocks = 2/CU
#define BIAS   4096.0f

// Fragment-ordered buffer xf: for 16-row tile t, k-slice kk (0..3), lane l (0..63):
//   bf16 index = t*2048 + kk*512 + l*8 + e
// = element (row = t*16 + (l&15), k = kk*32 + (l>>4)*8 + e) — the exact
// mfma_f32_16x16x32_bf16 A/B fragment layout. One tile = 4KB contiguous.

// ws layout
#define OFF_SQ    (2u << 20)
#define OFF_SQLAB (OFF_SQ + (64u << 10))     // float2 {sq, lab_bits} per col
#define OFF_D2P   (OFF_SQLAB + (64u << 10))
#define OFF_D2N   (OFF_D2P + (512u << 10))
#define OFF_ACC   (OFF_D2N + (512u << 10))   // float sum, int done

// global -> LDS direct copy, 16B per lane; LDS dest = wave-uniform base + lane*16
#define GLOAD_LDS(g, l) __builtin_amdgcn_global_load_lds(                     \
    (const __attribute__((address_space(1))) void*)(g),                       \
    (__attribute__((address_space(3))) void*)(l), 16, 0, 0)

// ---------------- prep: f32 -> bf16 fragment-order + norms + packed sq/lab ----------------
__global__ __launch_bounds__(256) void prep_kernel(const float* __restrict__ x,
                                                   const int* __restrict__ lab,
                                                   __hip_bfloat16* __restrict__ xf,
                                                   float* __restrict__ sq,
                                                   float2* __restrict__ sqlab,
                                                   float* __restrict__ acc_sum,
                                                   int* __restrict__ done) {
    if (blockIdx.x == 0 && threadIdx.x == 0) { acc_sum[0] = 0.f; done[0] = 0; }
    const int row  = blockIdx.x * 4 + (threadIdx.x >> 6);
    const int lane = threadIdx.x & 63;   // holds k = 2*lane, 2*lane+1
    const float2 v = *reinterpret_cast<const float2*>(x + row * DIM + lane * 2);
    __hip_bfloat162 b2;
    b2.x = __float2bfloat16(v.x);
    b2.y = __float2bfloat16(v.y);
    // fragment-order address for k0 = 2*lane
    const int kk = lane >> 4;
    const int g  = (lane >> 2) & 3;
    const int e  = (lane & 3) * 2;
    const int idx = (row >> 4) * 2048 + kk * 512 + (g * 16 + (row & 15)) * 8 + e;
    *reinterpret_cast<__hip_bfloat162*>(xf + idx) = b2;
    float s = v.x * v.x + v.y * v.y;
    #pragma unroll
    for (int m = 1; m < 64; m <<= 1) s += __shfl_xor(s, m, 64);
    if (lane == 0) {
        sq[row] = s;
        float2 p; p.x = s; p.y = __int_as_float(lab[row]);
        sqlab[row] = p;
    }
}

// ---------------- main: wave-private LDS ring + counted vmcnt, barrier-free loop ----------------
// grid = (NRB, NSPLIT), block = 256 (4 independent waves).
// Each wave owns 64 rows (A + max/min in regs) and streams the split's 32
// B-tiles through its PRIVATE 3-slot LDS ring via global_load_lds, waiting
// only vmcnt(8) per tile (tiles jt+1, jt+2 stay in flight). No loop barriers.
// t = sq_j - 2*dot + BIAS*same.  max t = hardest_pos + BIAS; min t = hardest_neg.
__global__ __launch_bounds__(256, 2) void main_kernel(
    const __hip_bfloat16* __restrict__ xf,
    const float* __restrict__ sq,
    const int*  __restrict__ lab,
    const float2* __restrict__ sqlab,
    float* __restrict__ d2p,   // [NSPLIT][B_ROWS]
    float* __restrict__ d2n) { // [NSPLIT][B_ROWS]
    __shared__ __align__(16) char ring[WAVES][3][4096];   // 48KB: per-wave 3-deep tile ring
    __shared__ __align__(16) char ldsS[4096];             // block-shared 512 x {sq, lab}

    const int tid  = threadIdx.x;
    const int lane = tid & 63;
    const int wave = tid >> 6;
    const int l15  = lane & 15;
    const int g    = lane >> 4;
    const int rowbase = blockIdx.x * BM + wave * RPW;
    const int split   = blockIdx.y;
    const int jstart  = split * JSPAN;

    const char* tilebase = (const char*)xf + (size_t)(jstart >> 4) * 4096;

    // ---- prologue: ring tiles 0..2 per wave; sqlab by wave 0; A frags; one barrier ----
    #pragma unroll
    for (int t = 0; t < 3; ++t) {
        #pragma unroll
        for (int p = 0; p < 4; ++p)
            GLOAD_LDS(tilebase + (size_t)t * 4096 + p * 1024 + lane * 16,
                      &ring[wave][t][p * 1024]);
    }
    if (wave == 0) {
        const char* gs = (const char*)sqlab + (size_t)jstart * 8;
        #pragma unroll
        for (int p = 0; p < 4; ++p)
            GLOAD_LDS(gs + p * 1024 + lane * 16, &ldsS[p * 1024]);
    }

    short8 a[4][4];
    #pragma unroll
    for (int s = 0; s < 4; ++s) {
        const __hip_bfloat16* ap = xf + ((size_t)(rowbase >> 4) + s) * 2048 + lane * 8;
        #pragma unroll
        for (int kk = 0; kk < 4; ++kk)
            a[s][kk] = *reinterpret_cast<const short8*>(ap + kk * 512);
    }
    int labi[4][4];
    #pragma unroll
    for (int s = 0; s < 4; ++s)
        #pragma unroll
        for (int q = 0; q < 4; ++q)
            labi[s][q] = lab[rowbase + s * 16 + g * 4 + q];

    float mx[4][4], mn[4][4];
    #pragma unroll
    for (int s = 0; s < 4; ++s)
        #pragma unroll
        for (int q = 0; q < 4; ++q) { mx[s][q] = -INFINITY; mn[s][q] = INFINITY; }

    __syncthreads();   // drains vmcnt(0): prologue stages + A loads all landed

    // ---- main loop: stage jt+2, wait vmcnt(8), consume jt. No barriers. ----
    for (int jt = 0; jt < NTILE; ++jt) {
        const int snext = (jt + 2) % 3;
        const unsigned tnext = (unsigned)((jt + 2) & 31);   // tail wrap: harmless restage
        #pragma unroll
        for (int p = 0; p < 4; ++p)
            GLOAD_LDS(tilebase + (size_t)tnext * 4096 + p * 1024 + lane * 16,
                      &ring[wave][snext][p * 1024]);

        asm volatile("s_waitcnt vmcnt(8)" ::: "memory");   // tiles jt+1, jt+2 in flight

        const int slot = jt % 3;
        short8 b[4];
        #pragma unroll
        for (int kk = 0; kk < 4; ++kk)
            b[kk] = *reinterpret_cast<const short8*>(&ring[wave][slot][kk * 1024 + lane * 16]);
        const floatx2 sl = *reinterpret_cast<const floatx2*>(&ldsS[(jt * 16 + l15) * 8]);
        const float sqj  = sl[0];
        const int   labj = __float_as_int(sl[1]);

        floatx4 acc[4];
        #pragma unroll
        for (int s = 0; s < 4; ++s) acc[s] = (floatx4){0.f, 0.f, 0.f, 0.f};
        #pragma unroll
        for (int kk = 0; kk < 4; ++kk) {
            #pragma unroll
            for (int s = 0; s < 4; ++s)
                acc[s] = __builtin_amdgcn_mfma_f32_16x16x32_bf16(a[s][kk], b[kk], acc[s], 0, 0, 0);
        }

        const float sqjb = sqj + BIAS;
        #pragma unroll
        for (int s = 0; s < 4; ++s) {
            #pragma unroll
            for (int q = 0; q < 4; ++q) {
                const float t = fmaf(-2.f, acc[s][q], (labj == labi[s][q]) ? sqjb : sqj);
                mx[s][q] = fmaxf(mx[s][q], t);
                mn[s][q] = fminf(mn[s][q], t);
            }
        }
    }

    // reduce over the 16 cols held by the 16 lanes of each g-group
    #pragma unroll
    for (int s = 0; s < 4; ++s)
        #pragma unroll
        for (int q = 0; q < 4; ++q) {
            #pragma unroll
            for (int mk = 1; mk < 16; mk <<= 1) {
                mx[s][q] = fmaxf(mx[s][q], __shfl_xor(mx[s][q], mk, 64));
                mn[s][q] = fminf(mn[s][q], __shfl_xor(mn[s][q], mk, 64));
            }
        }
    if (l15 == 0) {
        #pragma unroll
        for (int s = 0; s < 4; ++s)
            #pragma unroll
            for (int q = 0; q < 4; ++q) {
                const int i = rowbase + s * 16 + g * 4 + q;
                const float sqi = sq[i];
                d2p[split * B_ROWS + i] = sqi + (mx[s][q] - BIAS);
                d2n[split * B_ROWS + i] = sqi + mn[s][q];
            }
    }
}

// ---------------- combine: splits -> per-row loss -> scalar ----------------
__global__ __launch_bounds__(256) void combine_kernel(
    const float* __restrict__ d2p, const float* __restrict__ d2n,
    float* __restrict__ acc_sum, int* __restrict__ done,
    float* __restrict__ out) {
    const int row = blockIdx.x * 256 + threadIdx.x;
    float p = -INFINITY, n = INFINITY;
    #pragma unroll
    for (int s = 0; s < NSPLIT; ++s) {
        p = fmaxf(p, d2p[s * B_ROWS + row]);
        n = fminf(n, d2n[s * B_ROWS + row]);
    }
    float v = fmaxf(sqrtf(fmaxf(p, 0.f)) - sqrtf(fmaxf(n, 0.f)) + 1.0f, 0.f);
    #pragma unroll
    for (int mk = 1; mk < 64; mk <<= 1) v += __shfl_xor(v, mk, 64);
    __shared__ float sv[4];
    const int wv = threadIdx.x >> 6;
    if ((threadIdx.x & 63) == 0) sv[wv] = v;
    __syncthreads();
    if (threadIdx.x == 0) {
        atomicAdd(acc_sum, sv[0] + sv[1] + sv[2] + sv[3]);
        __threadfence();
        const int old = atomicAdd(done, 1);
        if (old == (int)gridDim.x - 1) {
            const float fs = atomicAdd(acc_sum, 0.f);   // coherent read
            out[0] = fs / (float)B_ROWS;
        }
    }
}

// ---------------- launch ----------------
extern "C" void kernel_launch(void* const* d_in, const int* in_sizes, int n_in,
                              void* d_out, int out_size, void* d_ws, size_t ws_size,
                              hipStream_t stream) {
    const float* x   = (const float*)d_in[0];
    const int*   lab = (const int*)d_in[1];
    float*       out = (float*)d_out;

    char* ws = (char*)d_ws;
    __hip_bfloat16* xf = (__hip_bfloat16*)ws;
    float*  sq      = (float*)(ws + OFF_SQ);
    float2* sqlab   = (float2*)(ws + OFF_SQLAB);
    float*  d2p     = (float*)(ws + OFF_D2P);
    float*  d2n     = (float*)(ws + OFF_D2N);
    float*  acc_sum = (float*)(ws + OFF_ACC);
    int*    done    = (int*)(ws + OFF_ACC + 4);

    prep_kernel<<<B_ROWS / 4, 256, 0, stream>>>(x, lab, xf, sq, sqlab, acc_sum, done);
    main_kernel<<<dim3(NRB, NSPLIT), 256, 0, stream>>>(xf, sq, lab, sqlab, d2p, d2n);
    combine_kernel<<<B_ROWS / 256, 256, 0, stream>>>(d2p, d2n, acc_sum, done, out);
}

// Round 9
// 44.013 us; speedup vs baseline: 1.0177x; 1.0177x over previous
//
#include <hip/hip_runtime.h>
#include <hip/hip_bf16.h>

typedef __attribute__((ext_vector_type(8))) short short8;
typedef __attribute__((ext_vector_type(4))) float floatx4;

#define B_ROWS 8192
#define DIM    128
#define NSPLIT 16
#define JSPAN  (B_ROWS / NSPLIT)        // 512 cols per split
#define NTILE  (JSPAN / 16)             // 32 j-tiles of 16 cols
#define WAVES  4
#define RPW    64                       // rows per wave (4 x 16-row MFMA sets)
#define BM     (WAVES * RPW)            // 256 rows per block
#define NRB    (B_ROWS / BM)            // 32 row-blocks -> 512 blocks = 2/CU
#define BIAS   4096.0f
#define KOFF   64.0f                    // keeps atomic keys strictly positive

// Fragment-ordered buffer xf: for 16-row tile t, k-slice kk (0..3), lane l (0..63):
//   bf16 index = t*2048 + kk*512 + l*8 + e
// = element (row = t*16 + (l&15), k = kk*32 + (l>>4)*8 + e) — the exact
// mfma_f32_16x16x32_bf16 A/B fragment layout. One tile = 4KB contiguous.

// ws layout
#define OFF_SQ  (2u << 20)                 // after 2MB xf
#define OFF_KP  (OFF_SQ + (64u << 10))     // int keys, 32KB
#define OFF_KN  (OFF_KP + (32u << 10))     // int keys, 32KB
#define OFF_ACC (OFF_KN + (32u << 10))     // float sum, int done

// ---------------- prep: coalesced fragment-order convert + norms + key init ----------------
// grid = 128 blocks x 256. Wave wv handles tile t = blockIdx*4+wv (512 tiles).
// Lane l: row = t*16 + (l&15); per kk reads 8 f32 (32B) at k = kk*32+(l>>4)*8,
// writes one coalesced 16B short8 chunk (wave: contiguous 1KB per kk).
__global__ __launch_bounds__(256) void prep_kernel(const float* __restrict__ x,
                                                   __hip_bfloat16* __restrict__ xf,
                                                   float* __restrict__ sq,
                                                   int* __restrict__ kp,
                                                   int* __restrict__ kn,
                                                   float* __restrict__ acc_sum,
                                                   int* __restrict__ done) {
    const int tid = threadIdx.x;
    const int gid = blockIdx.x * 256 + tid;
    if (gid < B_ROWS) { kp[gid] = 0; kn[gid] = 0x7F7F7F7F; }
    if (gid == 0) { acc_sum[0] = 0.f; done[0] = 0; }

    const int wv   = tid >> 6;
    const int lane = tid & 63;
    const int t    = blockIdx.x * 4 + wv;
    const int row  = t * 16 + (lane & 15);
    const float* xp = x + (size_t)row * DIM + (lane >> 4) * 8;

    float s = 0.f;
    #pragma unroll
    for (int kk = 0; kk < 4; ++kk) {
        const float4 v0 = *reinterpret_cast<const float4*>(xp + kk * 32);
        const float4 v1 = *reinterpret_cast<const float4*>(xp + kk * 32 + 4);
        short8 o;
        {
            __hip_bfloat16 h;
            h = __float2bfloat16(v0.x); o[0] = *reinterpret_cast<short*>(&h);
            h = __float2bfloat16(v0.y); o[1] = *reinterpret_cast<short*>(&h);
            h = __float2bfloat16(v0.z); o[2] = *reinterpret_cast<short*>(&h);
            h = __float2bfloat16(v0.w); o[3] = *reinterpret_cast<short*>(&h);
            h = __float2bfloat16(v1.x); o[4] = *reinterpret_cast<short*>(&h);
            h = __float2bfloat16(v1.y); o[5] = *reinterpret_cast<short*>(&h);
            h = __float2bfloat16(v1.z); o[6] = *reinterpret_cast<short*>(&h);
            h = __float2bfloat16(v1.w); o[7] = *reinterpret_cast<short*>(&h);
        }
        *reinterpret_cast<short8*>(xf + (size_t)t * 2048 + kk * 512 + lane * 8) = o;
        s += v0.x * v0.x + v0.y * v0.y + v0.z * v0.z + v0.w * v0.w
           + v1.x * v1.x + v1.y * v1.y + v1.z * v1.z + v1.w * v1.w;
    }
    s += __shfl_xor(s, 16, 64);
    s += __shfl_xor(s, 32, 64);
    if (lane < 16) sq[row] = s;
}

// ---------------- main: barrier-free Gram + biased hardest pos/neg, depth-4 reg ring ----------------
// grid = (NRB, NSPLIT), block = 256 (4 independent waves), 2 waves/SIMD.
// Wave owns 64 rows (A frags + running max/min in regs); streams the split's 32
// B-tiles through a 4-deep register ring (named buffers, consume-then-prefetch,
// distance ~3.5 tiles). t = sq_j - 2*dot + BIAS*same; immediate max/min merge.
// Output: per-row atomicMax/Min on int-punned positive keys (no split arrays).
__global__ __launch_bounds__(256, 2) void main_kernel(
    const __hip_bfloat16* __restrict__ xf,
    const float* __restrict__ sq,
    const int*  __restrict__ lab,
    int* __restrict__ kp,
    int* __restrict__ kn) {
    const int tid  = threadIdx.x;
    const int lane = tid & 63;
    const int wave = tid >> 6;
    const int l15  = lane & 15;
    const int g    = lane >> 4;
    const int rowbase = blockIdx.x * BM + wave * RPW;
    const int split   = blockIdx.y;
    const int jstart  = split * JSPAN;

    // A fragments: 4 sets x 16 rows, contiguous loads from xf
    short8 a[4][4];
    #pragma unroll
    for (int s = 0; s < 4; ++s) {
        const __hip_bfloat16* ap = xf + ((size_t)(rowbase >> 4) + s) * 2048 + lane * 8;
        #pragma unroll
        for (int kk = 0; kk < 4; ++kk)
            a[s][kk] = *reinterpret_cast<const short8*>(ap + kk * 512);
    }
    int labi[4][4];
    #pragma unroll
    for (int s = 0; s < 4; ++s)
        #pragma unroll
        for (int q = 0; q < 4; ++q)
            labi[s][q] = lab[rowbase + s * 16 + g * 4 + q];

    float mx[4][4], mn[4][4];
    #pragma unroll
    for (int s = 0; s < 4; ++s)
        #pragma unroll
        for (int q = 0; q < 4; ++q) { mx[s][q] = -INFINITY; mn[s][q] = INFINITY; }

    const __hip_bfloat16* bbase = xf + (size_t)(jstart >> 4) * 2048 + lane * 8;

    short8 b0[4], b1[4], b2[4], b3[4];
    float sq0, sq1, sq2, sq3;
    int   lb0, lb1, lb2, lb3;

    #define LOADT(BB, SQ, LB, T)                                               \
    do {                                                                       \
        const __hip_bfloat16* bp_ = bbase + (size_t)(T) * 2048;                \
        _Pragma("unroll")                                                      \
        for (int kk = 0; kk < 4; ++kk)                                         \
            BB[kk] = *reinterpret_cast<const short8*>(bp_ + kk * 512);         \
        SQ = sq[jstart + (T) * 16 + l15];                                      \
        LB = lab[jstart + (T) * 16 + l15];                                     \
    } while (0)

    #define STEP(BB, SQJ, LABJ)                                                \
    do {                                                                       \
        floatx4 acc[4];                                                        \
        _Pragma("unroll")                                                      \
        for (int s = 0; s < 4; ++s) acc[s] = (floatx4){0.f, 0.f, 0.f, 0.f};    \
        _Pragma("unroll")                                                      \
        for (int kk = 0; kk < 4; ++kk) {                                       \
            _Pragma("unroll")                                                  \
            for (int s = 0; s < 4; ++s)                                        \
                acc[s] = __builtin_amdgcn_mfma_f32_16x16x32_bf16(a[s][kk], BB[kk], acc[s], 0, 0, 0); \
        }                                                                      \
        const float sqjb_ = (SQJ) + BIAS;                                      \
        _Pragma("unroll")                                                      \
        for (int s = 0; s < 4; ++s) {                                          \
            _Pragma("unroll")                                                  \
            for (int q = 0; q < 4; ++q) {                                      \
                const float t_ = fmaf(-2.f, acc[s][q],                         \
                                      ((LABJ) == labi[s][q]) ? sqjb_ : (SQJ)); \
                mx[s][q] = fmaxf(mx[s][q], t_);                                \
                mn[s][q] = fminf(mn[s][q], t_);                                \
            }                                                                  \
        }                                                                      \
    } while (0)

    // prologue: fill the 4-deep ring
    LOADT(b0, sq0, lb0, 0);
    LOADT(b1, sq1, lb1, 1);
    LOADT(b2, sq2, lb2, 2);
    LOADT(b3, sq3, lb3, 3);

    for (int jt = 0; jt < NTILE; jt += 4) {
        STEP(b0, sq0, lb0); if (jt + 4 < NTILE) LOADT(b0, sq0, lb0, jt + 4);
        STEP(b1, sq1, lb1); if (jt + 5 < NTILE) LOADT(b1, sq1, lb1, jt + 5);
        STEP(b2, sq2, lb2); if (jt + 6 < NTILE) LOADT(b2, sq2, lb2, jt + 6);
        STEP(b3, sq3, lb3); if (jt + 7 < NTILE) LOADT(b3, sq3, lb3, jt + 7);
    }
    #undef STEP
    #undef LOADT

    // reduce over the 16 cols held by the 16 lanes of each g-group
    #pragma unroll
    for (int s = 0; s < 4; ++s)
        #pragma unroll
        for (int q = 0; q < 4; ++q) {
            #pragma unroll
            for (int mk = 1; mk < 16; mk <<= 1) {
                mx[s][q] = fmaxf(mx[s][q], __shfl_xor(mx[s][q], mk, 64));
                mn[s][q] = fminf(mn[s][q], __shfl_xor(mn[s][q], mk, 64));
            }
        }
    if (l15 == 0) {
        #pragma unroll
        for (int s = 0; s < 4; ++s)
            #pragma unroll
            for (int q = 0; q < 4; ++q) {
                const int i = rowbase + s * 16 + g * 4 + q;
                const float sqi = sq[i];
                // keys strictly positive: sqj-2dot >= -sqi-eps  =>  key >= KOFF-eps > 0
                const float kpv = sqi + mx[s][q] + KOFF;   // = hp2 + BIAS + KOFF
                const float knv = sqi + mn[s][q] + KOFF;   // = hn2 + KOFF
                atomicMax(&kp[i], __float_as_int(kpv));
                atomicMin(&kn[i], __float_as_int(knv));
            }
    }
}

// ---------------- combine: per-row loss -> scalar ----------------
__global__ __launch_bounds__(256) void combine_kernel(
    const int* __restrict__ kp, const int* __restrict__ kn,
    float* __restrict__ acc_sum, int* __restrict__ done,
    float* __restrict__ out) {
    const int row = blockIdx.x * 256 + threadIdx.x;
    const float hp2 = __int_as_float(kp[row]) - BIAS - KOFF;
    const float hn2 = __int_as_float(kn[row]) - KOFF;
    float v = fmaxf(sqrtf(fmaxf(hp2, 0.f)) - sqrtf(fmaxf(hn2, 0.f)) + 1.0f, 0.f);
    #pragma unroll
    for (int mk = 1; mk < 64; mk <<= 1) v += __shfl_xor(v, mk, 64);
    __shared__ float sv[4];
    const int wv = threadIdx.x >> 6;
    if ((threadIdx.x & 63) == 0) sv[wv] = v;
    __syncthreads();
    if (threadIdx.x == 0) {
        atomicAdd(acc_sum, sv[0] + sv[1] + sv[2] + sv[3]);
        __threadfence();
        const int old = atomicAdd(done, 1);
        if (old == (int)gridDim.x - 1) {
            const float fs = atomicAdd(acc_sum, 0.f);   // coherent read
            out[0] = fs / (float)B_ROWS;
        }
    }
}

// ---------------- launch ----------------
extern "C" void kernel_launch(void* const* d_in, const int* in_sizes, int n_in,
                              void* d_out, int out_size, void* d_ws, size_t ws_size,
                              hipStream_t stream) {
    const float* x   = (const float*)d_in[0];
    const int*   lab = (const int*)d_in[1];
    float*       out = (float*)d_out;

    char* ws = (char*)d_ws;
    __hip_bfloat16* xf = (__hip_bfloat16*)ws;
    float* sq      = (float*)(ws + OFF_SQ);
    int*   kp      = (int*)(ws + OFF_KP);
    int*   kn      = (int*)(ws + OFF_KN);
    float* acc_sum = (float*)(ws + OFF_ACC);
    int*   done    = (int*)(ws + OFF_ACC + 4);

    prep_kernel<<<B_ROWS / 64, 256, 0, stream>>>(x, xf, sq, kp, kn, acc_sum, done);
    main_kernel<<<dim3(NRB, NSPLIT), 256, 0, stream>>>(xf, sq, lab, kp, kn);
    combine_kernel<<<B_ROWS / 256, 256, 0, stream>>>(kp, kn, acc_sum, done, out);
}